// Round 4
// baseline (49084.726 us; speedup 1.0000x reference)
//
#include <hip/hip_runtime.h>
#include <hip/hip_cooperative_groups.h>

namespace cg = cooperative_groups;

#define TLEN 2048
#define NB   64
#define NH   256
#define NF   64
#define NCIN 16
#define NOUT 20
#define HB   (NH * NB)   // 16384 floats per h slot

// LLC-coherent (sc1) access helpers.
#define HL(p)    __hip_atomic_load((p),      __ATOMIC_RELAXED, __HIP_MEMORY_SCOPE_AGENT)
#define HS(p, v) __hip_atomic_store((p), (v), __ATOMIC_RELAXED, __HIP_MEMORY_SCOPE_AGENT)

// data-path load: SC1=true -> coherent-at-LLC atomic load (ring-reuse mode);
// SC1=false -> plain cached load (valid only when addresses are never reused
// within a dispatch: full-history mode; dispatch-start acquire + grid.sync
// guarantee no stale lines from previous replays).
template<bool SC1>
__device__ __forceinline__ float ldf(const float* p) {
    if constexpr (SC1) return HL(p);
    else               return *p;
}

__device__ __forceinline__ float sigf(float x) { return 1.0f / (1.0f + __expf(-x)); }
__device__ __forceinline__ float tanh_f(float x) {
    x = fminf(fmaxf(x, -15.0f), 15.0f);
    float e = __expf(2.0f * x);
    return (e - 1.0f) / (e + 1.0f);
}

// ---------------- Pass A: conv + relu, per-(f, t-quarter) partial sums for BN stats
__global__ __launch_bounds__(256) void conv_stats_kernel(
    const float* __restrict__ x, const float* __restrict__ cw, const float* __restrict__ cb,
    float* __restrict__ partials)
{
    const int blk = blockIdx.x;          // 256 blocks
    const int f = blk >> 2, tq = blk & 3;
    const int tid = threadIdx.x;

    float w[NCIN][3];
#pragma unroll
    for (int c = 0; c < NCIN; ++c) {
        w[c][0] = cw[(f * NCIN + c) * 3 + 0];
        w[c][1] = cw[(f * NCIN + c) * 3 + 1];
        w[c][2] = cw[(f * NCIN + c) * 3 + 2];
    }
    const float bias = cb[f];
    float s = 0.f, s2 = 0.f;

    for (int i = 0; i < 128; ++i) {
        int idx = tq * 32768 + i * 256 + tid;   // (B*T)/4 elements per block
        int b = idx >> 11;
        int t = idx & 2047;
        const float* xb = x + (size_t)b * NCIN * TLEN;
        float acc = bias;
#pragma unroll
        for (int c = 0; c < NCIN; ++c) {
            const float* xc = xb + (size_t)c * TLEN + t;
            float xm = (t > 0)        ? xc[-1] : 0.f;
            float x0 = xc[0];
            float xp = (t < TLEN - 1) ? xc[1]  : 0.f;
            acc = fmaf(xm, w[c][0], acc);
            acc = fmaf(x0, w[c][1], acc);
            acc = fmaf(xp, w[c][2], acc);
        }
        float y = fmaxf(acc, 0.f);
        s += y; s2 = fmaf(y, y, s2);
    }

    __shared__ float rs[256], rs2[256];
    rs[tid] = s; rs2[tid] = s2;
    __syncthreads();
    for (int off = 128; off > 0; off >>= 1) {
        if (tid < off) { rs[tid] += rs[tid + off]; rs2[tid] += rs2[tid + off]; }
        __syncthreads();
    }
    if (tid == 0) {
        partials[(f * 4 + tq) * 2 + 0] = rs[0];
        partials[(f * 4 + tq) * 2 + 1] = rs2[0];
    }
}

// ---------------- Pass B: conv + relu + BN affine, write feats[t][f][b]
__global__ __launch_bounds__(256) void conv_bn_feats_kernel(
    const float* __restrict__ x, const float* __restrict__ cw, const float* __restrict__ cb,
    const float* __restrict__ gamma, const float* __restrict__ beta,
    const float* __restrict__ partials, float* __restrict__ feats)
{
    const int t = blockIdx.x;            // 2048 blocks
    const int tid = threadIdx.x;
    const int b = tid & 63, fq = tid >> 6;

    __shared__ float sc[NF], sh[NF];
    if (tid < NF) {
        int f = tid;
        float s = 0.f, s2 = 0.f;
        for (int q = 0; q < 4; ++q) {
            s  += partials[(f * 4 + q) * 2 + 0];
            s2 += partials[(f * 4 + q) * 2 + 1];
        }
        const float inv_n = 1.0f / ((float)NB * (float)TLEN);
        float mean = s * inv_n;
        float var  = s2 * inv_n - mean * mean;
        float iv   = rsqrtf(var + 1e-5f);
        float scale = gamma[f] * iv;
        sc[f] = scale;
        sh[f] = beta[f] - mean * scale;
    }
    __syncthreads();

    float xr[NCIN][3];
    const float* xb = x + (size_t)b * NCIN * TLEN;
#pragma unroll
    for (int c = 0; c < NCIN; ++c) {
        const float* xc = xb + (size_t)c * TLEN + t;
        xr[c][0] = (t > 0)        ? xc[-1] : 0.f;
        xr[c][1] = xc[0];
        xr[c][2] = (t < TLEN - 1) ? xc[1]  : 0.f;
    }

    float* ft = feats + (size_t)t * (NF * NB);
    for (int fi = 0; fi < 16; ++fi) {
        int f = fq * 16 + fi;
        float acc = cb[f];
#pragma unroll
        for (int c = 0; c < NCIN; ++c) {
            acc = fmaf(xr[c][0], cw[(f * NCIN + c) * 3 + 0], acc);
            acc = fmaf(xr[c][1], cw[(f * NCIN + c) * 3 + 1], acc);
            acc = fmaf(xr[c][2], cw[(f * NCIN + c) * 3 + 2], acc);
        }
        float y = fmaxf(acc, 0.f);
        ft[f * NB + b] = fmaf(y, sc[f], sh[f]);
    }
}

#define QUAD() do { \
    a0 = fmaf(x0, w0.x, a0); a0 = fmaf(x1, w0.y, a0); a0 = fmaf(x2, w0.z, a0); a0 = fmaf(x3, w0.w, a0); \
    a1 = fmaf(x0, w1.x, a1); a1 = fmaf(x1, w1.y, a1); a1 = fmaf(x2, w1.z, a1); a1 = fmaf(x3, w1.w, a1); \
    a2 = fmaf(x0, w2.x, a2); a2 = fmaf(x1, w2.y, a2); a2 = fmaf(x2, w2.z, a2); a2 = fmaf(x3, w2.w, a2); \
    a3 = fmaf(x0, w3.x, a3); a3 = fmaf(x1, w3.y, a3); a3 = fmaf(x2, w3.z, a3); a3 = fmaf(x3, w3.w, a3); \
} while (0)

// ---------------- LSTM + FC kernel, decoupled flag sync
// RH0/RH1: ring depth of h0/h1 (2048 = full history, no reuse -> plain loads OK).
// SC1: use LLC-coherent loads for h (required when rings are reused).
// Producers publish via __syncthreads (vmcnt drain; sc1 stores ack at LLC) +
// tid0 RELAXED flag store. Consumers spin with RELAXED loads + value cache.
template<int RH0, int RH1, bool SC1>
__global__ __launch_bounds__(256) void lstm_kernel(
    const float* __restrict__ feats,
    const float* __restrict__ wih0, const float* __restrict__ whh0,
    const float* __restrict__ bih0, const float* __restrict__ bhh0,
    const float* __restrict__ wih1, const float* __restrict__ whh1,
    const float* __restrict__ bih1, const float* __restrict__ bhh1,
    const float* __restrict__ fcw,  const float* __restrict__ fcb,
    float* h0, float* h1,
    int* flag0, int* flag1,
    float* __restrict__ out)
{
    cg::grid_group grid = cg::this_grid();
    const int blk = blockIdx.x;
    const int tid = threadIdx.x;
    const int b  = tid & 63;
    const int q  = tid >> 6;   // wave id 0..3
    const int u  = q & 1;      // which of the block's 2 hidden units
    const int kh = q >> 1;     // which K-half
    const bool isL1 = (blk >= 128);
    const int j0 = (isL1 ? blk - 128 : blk) * 2;

    __shared__ float  W[8 * 512];      // rows: [u*4+gate][k], stride 512
    __shared__ float  bias8[8];
    __shared__ float4 red4[2][64];
    __shared__ float  red1[4][64];

    // ---- load weights into LDS (once)
    for (int r = 0; r < 8; ++r) {
        int uu = r >> 2, g = r & 3;
        int grow = g * 256 + j0 + uu;   // PyTorch gate order i,f,g,o
        if (!isL1) {
            for (int k = tid; k < 320; k += 256)
                W[r * 512 + k] = (k < 64) ? wih0[grow * 64 + k] : whh0[grow * 256 + (k - 64)];
        } else {
            for (int k = tid; k < 512; k += 256)
                W[r * 512 + k] = (k < 256) ? wih1[grow * 256 + k] : whh1[grow * 256 + (k - 256)];
        }
    }
    if (tid < 8) {
        int r = tid, uu = r >> 2, g = r & 3;
        int grow = g * 256 + j0 + uu;
        bias8[r] = isL1 ? (bih1[grow] + bhh1[grow]) : (bih0[grow] + bhh0[grow]);
    }
    // ---- reset own flag + zero initial state (grid.sync below publishes globally)
    if (tid == 0) {
        if (!isL1) HS(&flag0[blk], 0);
        else       HS(&flag1[blk - 128], 0);
    }
    if (tid < 128) {
        int uu = tid >> 6, bb = tid & 63;
        int j = j0 + uu;
        if (!isL1) HS(&h0[(size_t)(RH0 - 1) * HB + j * 64 + bb], 0.f);  // h0[-1]
        else       HS(&h1[(size_t)(RH1 - 1) * HB + j * 64 + bb], 0.f);  // h1[-1]
    }
    float c_reg = 0.f;                 // cell state, tid<128 threads own (u=q,b)
    int fcache = 0;                    // per-thread cached flag value (monotone)
    __syncthreads();
    grid.sync();   // the only grid-wide barrier: publishes flag zeroing + init state

    const float4* W0v = (const float4*)(W + (u * 4 + 0) * 512);
    const float4* W1v = (const float4*)(W + (u * 4 + 1) * 512);
    const float4* W2v = (const float4*)(W + (u * 4 + 2) * 512);
    const float4* W3v = (const float4*)(W + (u * 4 + 3) * 512);

    if (!isL1) {
        // =============== layer 0 blocks ===============
        for (int s = 0; s < TLEN; ++s) {
            // wait: all flag0 >= s ; ring guard only if RH0 < TLEN
            const int thrB = s - (RH0 - 1);
            for (;;) {
                bool ok;
                if (tid < 128) { if (fcache < s) fcache = HL(&flag0[tid]); ok = fcache >= s; }
                else {
                    if (RH0 >= TLEN) ok = true;     // full history: no overwrite ever
                    else { if (fcache < thrB) fcache = HL(&flag1[tid - 128]); ok = fcache >= thrB; }
                }
                if (__syncthreads_count(ok) == 256) break;
                __builtin_amdgcn_s_sleep(2);
            }
            const float* h0prev = h0 + (size_t)((s + RH0 - 1) & (RH0 - 1)) * HB;   // step s-1
            float a0, a1, a2, a3;
            if (kh == 0) {
                a0 = bias8[u * 4 + 0]; a1 = bias8[u * 4 + 1];
                a2 = bias8[u * 4 + 2]; a3 = bias8[u * 4 + 3];
                const float* fp = feats + (size_t)s * (NF * NB) + b;
#pragma unroll 4
                for (int k4 = 0; k4 < 16; ++k4) {            // k 0..63 : conv feats (plain)
                    float4 w0 = W0v[k4], w1 = W1v[k4], w2 = W2v[k4], w3 = W3v[k4];
                    float x0 = fp[(4 * k4 + 0) * 64], x1 = fp[(4 * k4 + 1) * 64];
                    float x2 = fp[(4 * k4 + 2) * 64], x3 = fp[(4 * k4 + 3) * 64];
                    QUAD();
                }
                const float* hp = h0prev + b;
#pragma unroll 8
                for (int k4 = 16; k4 < 40; ++k4) {           // k 64..159 : h0 rows 0..95
                    float4 w0 = W0v[k4], w1 = W1v[k4], w2 = W2v[k4], w3 = W3v[k4];
                    int hk = 4 * k4 - 64;
                    float x0 = ldf<SC1>(hp + (hk + 0) * 64), x1 = ldf<SC1>(hp + (hk + 1) * 64);
                    float x2 = ldf<SC1>(hp + (hk + 2) * 64), x3 = ldf<SC1>(hp + (hk + 3) * 64);
                    QUAD();
                }
            } else {
                a0 = a1 = a2 = a3 = 0.f;
                const float* hp = h0prev + b;
#pragma unroll 8
                for (int k4 = 40; k4 < 80; ++k4) {           // k 160..319 : h0 rows 96..255
                    float4 w0 = W0v[k4], w1 = W1v[k4], w2 = W2v[k4], w3 = W3v[k4];
                    int hk = 4 * k4 - 64;
                    float x0 = ldf<SC1>(hp + (hk + 0) * 64), x1 = ldf<SC1>(hp + (hk + 1) * 64);
                    float x2 = ldf<SC1>(hp + (hk + 2) * 64), x3 = ldf<SC1>(hp + (hk + 3) * 64);
                    QUAD();
                }
                red4[u][b] = make_float4(a0, a1, a2, a3);
            }
            __syncthreads();
            if (kh == 0) {
                float4 r = red4[u][b];
                float gi = a0 + r.x, gf = a1 + r.y, gg = a2 + r.z, go = a3 + r.w;
                int j = j0 + u;
                float i_ = sigf(gi), f_ = sigf(gf), g_ = tanh_f(gg), o_ = sigf(go);
                c_reg = fmaf(f_, c_reg, i_ * g_);
                float h = o_ * tanh_f(c_reg);
                HS(&h0[(size_t)(s & (RH0 - 1)) * HB + j * 64 + b], h);   // sc1: lands at LLC
            }
            __syncthreads();   // drains all waves' vmcnt -> h visible at LLC
            if (tid == 0) HS(&flag0[blk], s + 1);   // RELAXED publish (ordering by barrier)
        }
    } else {
        // =============== layer 1 blocks ===============
        const int jb = blk - 128;
        const bool doFC = (jb < NOUT);
        for (int s = 0; s < TLEN; ++s) {
            // wait: all flag0 >= s+1 (h0[s] ready) ; all flag1 >= s (h1[s-1] ready)
            for (;;) {
                bool ok;
                if (tid < 128) { if (fcache < s + 1) fcache = HL(&flag0[tid]);       ok = fcache >= s + 1; }
                else           { if (fcache < s)     fcache = HL(&flag1[tid - 128]); ok = fcache >= s; }
                if (__syncthreads_count(ok) == 256) break;
                __builtin_amdgcn_s_sleep(2);
            }
            const float* h0cur  = h0 + (size_t)(s & (RH0 - 1)) * HB;               // step s
            const float* h1prev = h1 + (size_t)((s + RH1 - 1) & (RH1 - 1)) * HB;   // step s-1

            const float* Xs = ((kh == 0) ? h0cur : h1prev) + b;
            const int kbase = kh * 64;
            float a0, a1, a2, a3;
            if (kh == 0) {
                a0 = bias8[u * 4 + 0]; a1 = bias8[u * 4 + 1];
                a2 = bias8[u * 4 + 2]; a3 = bias8[u * 4 + 3];
            } else { a0 = a1 = a2 = a3 = 0.f; }
#pragma unroll 8
            for (int k4 = 0; k4 < 64; ++k4) {
                float4 w0 = W0v[kbase + k4], w1 = W1v[kbase + k4];
                float4 w2 = W2v[kbase + k4], w3 = W3v[kbase + k4];
                float x0 = ldf<SC1>(Xs + (4 * k4 + 0) * 64), x1 = ldf<SC1>(Xs + (4 * k4 + 1) * 64);
                float x2 = ldf<SC1>(Xs + (4 * k4 + 2) * 64), x3 = ldf<SC1>(Xs + (4 * k4 + 3) * 64);
                QUAD();
            }
            if (kh == 1) red4[u][b] = make_float4(a0, a1, a2, a3);
            __syncthreads();
            if (kh == 0) {
                float4 r = red4[u][b];
                float gi = a0 + r.x, gf = a1 + r.y, gg = a2 + r.z, go = a3 + r.w;
                int j = j0 + u;
                float i_ = sigf(gi), f_ = sigf(gf), g_ = tanh_f(gg), o_ = sigf(go);
                c_reg = fmaf(f_, c_reg, i_ * g_);
                float h = o_ * tanh_f(c_reg);
                HS(&h1[(size_t)(s & (RH1 - 1)) * HB + j * 64 + b], h);
            }
            __syncthreads();   // drains vmcnt -> h1 visible at LLC
            if (tid == 0) HS(&flag1[jb], s + 1);   // RELAXED publish

            // FC for t=s-1 AFTER publish: off the critical path. Safe: slot (s-1)%RH1
            // is next overwritten at step s-1+RH1 >= s+3, which requires our flag1 >= s+3.
            if (doFC && s >= 1) {
                const float* fw = fcw + jb * NH + q * 64;
                const float* hp = h1prev + q * 64 * NB + b;
                float acc = 0.f;
#pragma unroll 8
                for (int k = 0; k < 64; ++k) acc = fmaf(ldf<SC1>(hp + k * 64), fw[k], acc);
                red1[q][b] = acc;
                __syncthreads();
                if (q == 0) {
                    float sres = red1[0][b] + red1[1][b] + red1[2][b] + red1[3][b] + fcb[jb];
                    out[((size_t)b * NOUT + jb) * TLEN + (s - 1)] = sres;
                }
            }
        }
        // epilogue: FC for t = TLEN-1 (needs all h1[TLEN-1])
        if (doFC) {
            for (;;) {
                int v = 0x7fffffff;
                if (tid < 128) v = HL(&flag1[tid]);
                if (__syncthreads_count(v >= TLEN) == 256) break;
                __builtin_amdgcn_s_sleep(2);
            }
            const float* hlast = h1 + (size_t)((TLEN - 1) & (RH1 - 1)) * HB;
            const float* fw = fcw + jb * NH + q * 64;
            const float* hp = hlast + q * 64 * NB + b;
            float acc = 0.f;
#pragma unroll 8
            for (int k = 0; k < 64; ++k) acc = fmaf(ldf<SC1>(hp + k * 64), fw[k], acc);
            red1[q][b] = acc;
            __syncthreads();
            if (q == 0) {
                float sres = red1[0][b] + red1[1][b] + red1[2][b] + red1[3][b] + fcb[jb];
                out[((size_t)b * NOUT + jb) * TLEN + (TLEN - 1)] = sres;
            }
        }
    }
}

extern "C" void kernel_launch(void* const* d_in, const int* in_sizes, int n_in,
                              void* d_out, int out_size, void* d_ws, size_t ws_size,
                              hipStream_t stream) {
    (void)in_sizes; (void)n_in; (void)out_size;
    const float* x      = (const float*)d_in[0];
    const float* conv_w = (const float*)d_in[1];
    const float* conv_b = (const float*)d_in[2];
    const float* gamma  = (const float*)d_in[3];
    const float* beta   = (const float*)d_in[4];
    const float* wih0   = (const float*)d_in[5];
    const float* whh0   = (const float*)d_in[6];
    const float* bih0   = (const float*)d_in[7];
    const float* bhh0   = (const float*)d_in[8];
    const float* wih1   = (const float*)d_in[9];
    const float* whh1   = (const float*)d_in[10];
    const float* bih1   = (const float*)d_in[11];
    const float* bhh1   = (const float*)d_in[12];
    const float* fcw    = (const float*)d_in[13];
    const float* fcb    = (const float*)d_in[14];
    float* out = (float*)d_out;

    char* ws = (char*)d_ws;
    const size_t FEATS_B = (size_t)TLEN * NF * NB * 4;           // 33,554,432
    const size_t SLOT_B  = (size_t)HB * 4;                       // 65,536

    // full-history layout: h0[2048 slots] h1[2048 slots] flags feats partials
    const size_t H_FULL  = (size_t)TLEN * SLOT_B;                // 134,217,728 each
    const size_t need_full = 2 * H_FULL + 4096 + FEATS_B + 4096;

    void* kfun;
    float *h0, *h1, *feats, *partials;
    int *flag0, *flag1;

    if (ws_size >= need_full) {
        h0       = (float*)(ws);
        h1       = (float*)(ws + H_FULL);
        flag0    = (int*)  (ws + 2 * H_FULL);
        flag1    = flag0 + 128;
        feats    = (float*)(ws + 2 * H_FULL + 4096);
        partials = (float*)(ws + 2 * H_FULL + 4096 + FEATS_B);
        kfun = reinterpret_cast<void*>(&lstm_kernel<TLEN, TLEN, false>);
    } else {
        // fallback: ring buffers + sc1 coherent loads (round-3 path, relaxed publish)
        feats    = (float*)(ws);
        partials = (float*)(ws + FEATS_B);
        h0       = (float*)(ws + FEATS_B + 4096);                // 8 slots
        h1       = (float*)(ws + FEATS_B + 4096 + 8 * SLOT_B);   // 4 slots
        flag0    = (int*)  (ws + FEATS_B + 4096 + 12 * SLOT_B);
        flag1    = flag0 + 128;
        kfun = reinterpret_cast<void*>(&lstm_kernel<8, 4, true>);
    }

    hipLaunchKernelGGL(conv_stats_kernel, dim3(256), dim3(256), 0, stream,
                       x, conv_w, conv_b, partials);
    hipLaunchKernelGGL(conv_bn_feats_kernel, dim3(2048), dim3(256), 0, stream,
                       x, conv_w, conv_b, gamma, beta, partials, feats);

    void* args[] = { (void*)&feats,
                     (void*)&wih0, (void*)&whh0, (void*)&bih0, (void*)&bhh0,
                     (void*)&wih1, (void*)&whh1, (void*)&bih1, (void*)&bhh1,
                     (void*)&fcw,  (void*)&fcb,
                     (void*)&h0, (void*)&h1, (void*)&flag0, (void*)&flag1,
                     (void*)&out };
    hipLaunchCooperativeKernel(kfun, dim3(256), dim3(256), args, 0, stream);
}

// Round 7
// 24146.471 us; speedup vs baseline: 2.0328x; 2.0328x over previous
//
#include <hip/hip_runtime.h>

#define TLEN 2048
#define NB   64
#define NH   256
#define NF   64
#define NCIN 16
#define NOUT 20
#define NG   8              // batch groups
#define GS   8              // samples per group
#define SLU  16             // hidden units per slice (block)
#define GSLAB (NH * GS)     // 2048 floats: one group's h slab [unit][sample]

// LLC-coherent (sc1) access helpers.
#define HL(p)    __hip_atomic_load((p),      __ATOMIC_RELAXED, __HIP_MEMORY_SCOPE_AGENT)
#define HS(p, v) __hip_atomic_store((p), (v), __ATOMIC_RELAXED, __HIP_MEMORY_SCOPE_AGENT)

__device__ __forceinline__ float sigf(float x) { return 1.0f / (1.0f + __expf(-x)); }
__device__ __forceinline__ float tanh_f(float x) {
    x = fminf(fmaxf(x, -15.0f), 15.0f);
    float e = __expf(2.0f * x);
    return (e - 1.0f) / (e + 1.0f);
}

// NOTE: parameter must NOT be named `w` — `xv.w` would get macro-substituted.
#define FMA4(acc, xv, ww) do { \
    acc.x = fmaf(xv.x, (ww), acc.x); \
    acc.y = fmaf(xv.y, (ww), acc.y); \
    acc.z = fmaf(xv.z, (ww), acc.z); \
    acc.w = fmaf(xv.w, (ww), acc.w); } while (0)

#define RED32(vv) do { \
    vv.x += __shfl_xor(vv.x, 32); vv.y += __shfl_xor(vv.y, 32); \
    vv.z += __shfl_xor(vv.z, 32); vv.w += __shfl_xor(vv.w, 32); } while (0)

// ---------------- Pass A: conv + relu, per-(f, t-quarter) partial sums for BN stats
__global__ __launch_bounds__(256) void conv_stats_kernel(
    const float* __restrict__ x, const float* __restrict__ cw, const float* __restrict__ cb,
    float* __restrict__ partials)
{
    const int blk = blockIdx.x;          // 256 blocks
    const int f = blk >> 2, tq = blk & 3;
    const int tid = threadIdx.x;

    float w[NCIN][3];
#pragma unroll
    for (int c = 0; c < NCIN; ++c) {
        w[c][0] = cw[(f * NCIN + c) * 3 + 0];
        w[c][1] = cw[(f * NCIN + c) * 3 + 1];
        w[c][2] = cw[(f * NCIN + c) * 3 + 2];
    }
    const float bias = cb[f];
    float s = 0.f, s2 = 0.f;

    for (int i = 0; i < 128; ++i) {
        int idx = tq * 32768 + i * 256 + tid;   // (B*T)/4 elements per block
        int b = idx >> 11;
        int t = idx & 2047;
        const float* xb = x + (size_t)b * NCIN * TLEN;
        float acc = bias;
#pragma unroll
        for (int c = 0; c < NCIN; ++c) {
            const float* xc = xb + (size_t)c * TLEN + t;
            float xm = (t > 0)        ? xc[-1] : 0.f;
            float x0 = xc[0];
            float xp = (t < TLEN - 1) ? xc[1]  : 0.f;
            acc = fmaf(xm, w[c][0], acc);
            acc = fmaf(x0, w[c][1], acc);
            acc = fmaf(xp, w[c][2], acc);
        }
        float y = fmaxf(acc, 0.f);
        s += y; s2 = fmaf(y, y, s2);
    }

    __shared__ float rs[256], rs2[256];
    rs[tid] = s; rs2[tid] = s2;
    __syncthreads();
    for (int off = 128; off > 0; off >>= 1) {
        if (tid < off) { rs[tid] += rs[tid + off]; rs2[tid] += rs2[tid + off]; }
        __syncthreads();
    }
    if (tid == 0) {
        partials[(f * 4 + tq) * 2 + 0] = rs[0];
        partials[(f * 4 + tq) * 2 + 1] = rs2[0];
    }
}

// ---------------- Pass B: conv + relu + BN affine, write feats[t][g][f][bl]
__global__ __launch_bounds__(256) void conv_bn_feats_kernel(
    const float* __restrict__ x, const float* __restrict__ cw, const float* __restrict__ cb,
    const float* __restrict__ gamma, const float* __restrict__ beta,
    const float* __restrict__ partials, float* __restrict__ feats)
{
    const int t = blockIdx.x;            // 2048 blocks
    const int tid = threadIdx.x;
    const int b = tid & 63, fq = tid >> 6;

    __shared__ float sc[NF], sh[NF];
    if (tid < NF) {
        int f = tid;
        float s = 0.f, s2 = 0.f;
        for (int q = 0; q < 4; ++q) {
            s  += partials[(f * 4 + q) * 2 + 0];
            s2 += partials[(f * 4 + q) * 2 + 1];
        }
        const float inv_n = 1.0f / ((float)NB * (float)TLEN);
        float mean = s * inv_n;
        float var  = s2 * inv_n - mean * mean;
        float iv   = rsqrtf(var + 1e-5f);
        float scale = gamma[f] * iv;
        sc[f] = scale;
        sh[f] = beta[f] - mean * scale;
    }
    __syncthreads();

    float xr[NCIN][3];
    const float* xb = x + (size_t)b * NCIN * TLEN;
#pragma unroll
    for (int c = 0; c < NCIN; ++c) {
        const float* xc = xb + (size_t)c * TLEN + t;
        xr[c][0] = (t > 0)        ? xc[-1] : 0.f;
        xr[c][1] = xc[0];
        xr[c][2] = (t < TLEN - 1) ? xc[1]  : 0.f;
    }

    float* ft = feats + (size_t)t * (NG * NF * GS);
    for (int fi = 0; fi < 16; ++fi) {
        int f = fq * 16 + fi;
        float acc = cb[f];
#pragma unroll
        for (int c = 0; c < NCIN; ++c) {
            acc = fmaf(xr[c][0], cw[(f * NCIN + c) * 3 + 0], acc);
            acc = fmaf(xr[c][1], cw[(f * NCIN + c) * 3 + 1], acc);
            acc = fmaf(xr[c][2], cw[(f * NCIN + c) * 3 + 2], acc);
        }
        float y = fmaxf(acc, 0.f);
        ft[((b >> 3) * NF + f) * GS + (b & 7)] = fmaf(y, sc[f], sh[f]);
    }
}

template<int NSLOT>
__device__ __forceinline__ size_t slotidx(int x) {
    if constexpr (NSLOT > TLEN) return (size_t)x;
    else return (size_t)(x % NSLOT);
}

template<bool SC1>
__device__ __forceinline__ void stage_slab(float* dst, const float* src, int tid) {
    if constexpr (!SC1) {
        float4* d4 = (float4*)dst;
        const float4* s4 = (const float4*)src;
        d4[tid] = s4[tid];
        d4[tid + 256] = s4[tid + 256];
    } else {
        for (int i = tid; i < GSLAB; i += 256) dst[i] = HL(src + i);
    }
}

// ---------------- per-layer driver, runs inside lstm_kernel
// Block = one (group g, slice sl) of one layer. 256 threads:
//   jp = tid&7 (unit pair jp, jp+8), g4 = (tid>>3)&3 (gate), kq = tid>>5 (K-eighth)
// Weights live in VGPRs (wa/wb, K/8 each). x slab staged to LDS per step.
// Flags + h slot-0 are zeroed by hipMemsetAsync BEFORE this dispatch (stream
// ordering replaces the old cooperative grid.sync; no cg needed).
template<int K, bool ISL1, int NSLOT, bool SC1>
__device__ __forceinline__ void run_layer(
    int g, int sl, int tid,
    const float* __restrict__ xin,   // !ISL1: feats ; ISL1: h0 history
    const float* __restrict__ wih, const float* __restrict__ whh,
    const float* __restrict__ bih, const float* __restrict__ bhh,
    const float* __restrict__ fcw, const float* __restrict__ fcb,
    float* houth, int* flags, float* __restrict__ out,
    float* xs, float* red, float (*biasS)[SLU], float (*redf)[16])
{
    constexpr int K8 = K / 8;
    const int jp = tid & 7;
    const int g4 = (tid >> 3) & 3;
    const int kq = tid >> 5;
    const int kqBase = kq * K8;
    const int rowA = g4 * 256 + sl * SLU + jp;
    const int rowB = rowA + 8;

    // ---- weights -> registers (once)
    float wa[K8], wb[K8];
#pragma unroll
    for (int kk = 0; kk < K8; ++kk) {
        int k = kqBase + kk;
        if constexpr (!ISL1) {
            wa[kk] = (k < NF) ? wih[rowA * NF + k] : whh[rowA * NH + (k - NF)];
            wb[kk] = (k < NF) ? wih[rowB * NF + k] : whh[rowB * NH + (k - NF)];
        } else {
            wa[kk] = (k < NH) ? wih[rowA * NH + k] : whh[rowA * NH + (k - NH)];
            wb[kk] = (k < NH) ? wih[rowB * NH + k] : whh[rowB * NH + (k - NH)];
        }
    }
    if (tid < 64) {
        int gg = tid >> 4, jj = tid & 15, grow = gg * 256 + sl * SLU + jj;
        biasS[gg][jj] = bih[grow] + bhh[grow];
    }
    __syncthreads();

    const int fj = tid >> 3, fb = tid & 7;  // finalizer mapping (tid<128)
    float c_reg = 0.f;
    int fc = 0;                              // cached flag value (monotone)
    float4* xs4 = (float4*)xs;

    for (int s = 0; s < TLEN; ++s) {
        // ---- spin on group flag line (one 128B line: 16 L0 + 16 L1 flags)
        for (;;) {
            bool ok = true;
            if (tid < 16) {
                int thr = ISL1 ? s + 1 : s;
                if (fc < thr) fc = HL(&flags[g * 32 + tid]);
                ok = fc >= thr;
            } else if (tid < 32) {
                if constexpr (ISL1) {
                    if (fc < s) fc = HL(&flags[g * 32 + tid]);
                    ok = fc >= s;
                } else if constexpr (NSLOT <= TLEN) {
                    int thr = s + 2 - NSLOT;   // ring overwrite guard vs L1 readers
                    if (fc < thr) fc = HL(&flags[g * 32 + tid]);
                    ok = fc >= thr;
                }
            }
            if (__syncthreads_count(ok) == 256) break;
            __builtin_amdgcn_s_sleep(1);
        }

        // ---- stage x slab(s) into LDS  (xs layout: [k][b], b inner)
        const float* hprev = houth + (slotidx<NSLOT>(s) * NG + g) * GSLAB;
        if constexpr (!ISL1) {
            const float4* fsrc = (const float4*)(xin + ((size_t)s * NG + g) * (NF * GS));
            if (tid < 128) xs4[tid] = fsrc[tid];
            stage_slab<SC1>(xs + NF * GS, hprev, tid);
        } else {
            const float* h0cur = xin + (slotidx<NSLOT>(s + 1) * NG + g) * GSLAB;
            stage_slab<SC1>(xs, h0cur, tid);
            stage_slab<SC1>(xs + NH * GS, hprev, tid);
        }
        __syncthreads();

        // ---- gate GEMM: acc over (2 units x 8 samples), K-eighth per thread
        float4 aA0 = {0,0,0,0}, aA1 = {0,0,0,0}, aB0 = {0,0,0,0}, aB1 = {0,0,0,0};
        const float* xsk = xs + kqBase * GS;
#pragma unroll
        for (int kk = 0; kk < K8; ++kk) {
            float4 x0 = *(const float4*)(xsk + kk * GS);
            float4 x1 = *(const float4*)(xsk + kk * GS + 4);
            float wAv = wa[kk], wBv = wb[kk];
            FMA4(aA0, x0, wAv); FMA4(aA1, x1, wAv);
            FMA4(aB0, x0, wBv); FMA4(aB1, x1, wBv);
        }
        // reduce kq pairs within wave (lane ^ 32), then 4 wave-partials via LDS
        RED32(aA0); RED32(aA1); RED32(aB0); RED32(aB1);
        if ((tid & 32) == 0) {
            int gk = g4 * 4 + (tid >> 6);          // [gate][kq2]
            float4* r4 = (float4*)red;
            r4[gk * 32 + jp * 2 + 0]       = aA0;
            r4[gk * 32 + jp * 2 + 1]       = aA1;
            r4[gk * 32 + (jp + 8) * 2 + 0] = aB0;
            r4[gk * 32 + (jp + 8) * 2 + 1] = aB1;
        }
        __syncthreads();

        // ---- finalize: sum 4 kq2-partials per gate, activations, cell update
        if (tid < 128) {
            float gate[4];
#pragma unroll
            for (int gg = 0; gg < 4; ++gg) {
                float s0 = 0.f;
#pragma unroll
                for (int k2 = 0; k2 < 4; ++k2)
                    s0 += red[(gg * 4 + k2) * 128 + fj * 8 + fb];
                gate[gg] = s0 + biasS[gg][fj];
            }
            float i_ = sigf(gate[0]), f_ = sigf(gate[1]);
            float g_ = tanh_f(gate[2]), o_ = sigf(gate[3]);
            c_reg = fmaf(f_, c_reg, i_ * g_);
            float h = o_ * tanh_f(c_reg);
            float* hout = houth + (slotidx<NSLOT>(s + 1) * NG + g) * GSLAB;
            HS(&hout[(sl * SLU + fj) * GS + fb], h);
        }
        __syncthreads();   // drain h stores (vmcnt) before publish
        if (tid == 0) HS(&flags[g * 32 + (ISL1 ? 16 : 0) + sl], s + 1);

        // ---- FC for t = s-1 from the staged h1prev slab (off critical path)
        if constexpr (ISL1) {
            if (s >= 1) {
                if (tid < 160) {
                    int m = tid >> 4, seg = tid & 15;
                    int fo = sl * 10 + m, o = fo >> 3, b = fo & 7;
                    const float* fwr = fcw + o * NH + seg * 16;
                    const float* xr = xs + (NH + seg * 16) * GS + b;
                    float p = 0.f;
#pragma unroll
                    for (int kk2 = 0; kk2 < 16; ++kk2) p = fmaf(fwr[kk2], xr[kk2 * GS], p);
                    redf[m][seg] = p;
                }
                __syncthreads();
                if (tid < 10) {
                    int fo = sl * 10 + tid, o = fo >> 3, b = fo & 7;
                    float s0 = 0.f;
#pragma unroll
                    for (int seg = 0; seg < 16; ++seg) s0 += redf[tid][seg];
                    out[((size_t)(g * GS + b) * NOUT + o) * TLEN + (s - 1)] = s0 + fcb[o];
                }
            }
        }
    }

    // ---- epilogue FC for t = TLEN-1
    if constexpr (ISL1) {
        for (;;) {
            bool ok = true;
            if (tid >= 16 && tid < 32) {
                if (fc < TLEN) fc = HL(&flags[g * 32 + tid]);
                ok = fc >= TLEN;
            }
            if (__syncthreads_count(ok) == 256) break;
            __builtin_amdgcn_s_sleep(1);
        }
        const float* hlast = houth + (slotidx<NSLOT>(TLEN) * NG + g) * GSLAB;
        stage_slab<SC1>(xs + NH * GS, hlast, tid);
        __syncthreads();
        if (tid < 160) {
            int m = tid >> 4, seg = tid & 15;
            int fo = sl * 10 + m, o = fo >> 3, b = fo & 7;
            const float* fwr = fcw + o * NH + seg * 16;
            const float* xr = xs + (NH + seg * 16) * GS + b;
            float p = 0.f;
#pragma unroll
            for (int kk2 = 0; kk2 < 16; ++kk2) p = fmaf(fwr[kk2], xr[kk2 * GS], p);
            redf[m][seg] = p;
        }
        __syncthreads();
        if (tid < 10) {
            int fo = sl * 10 + tid, o = fo >> 3, b = fo & 7;
            float s0 = 0.f;
#pragma unroll
            for (int seg = 0; seg < 16; ++seg) s0 += redf[tid][seg];
            out[((size_t)(g * GS + b) * NOUT + o) * TLEN + (TLEN - 1)] = s0 + fcb[o];
        }
    }
}

// Grid: 256 blocks x 256 threads, PLAIN launch (no cooperative machinery).
// Block (g, r): r<16 -> L0 slice r; r>=16 -> L1 slice r-16.
template<int NSLOT, bool SC1>
__global__ __launch_bounds__(256, 2) void lstm_kernel(
    const float* __restrict__ feats,
    const float* __restrict__ wih0, const float* __restrict__ whh0,
    const float* __restrict__ bih0, const float* __restrict__ bhh0,
    const float* __restrict__ wih1, const float* __restrict__ whh1,
    const float* __restrict__ bih1, const float* __restrict__ bhh1,
    const float* __restrict__ fcw,  const float* __restrict__ fcb,
    float* h0h, float* h1h, int* flags, float* __restrict__ out)
{
    __shared__ float xs[512 * GS];        // 16 KB: x slab [k][b]
    __shared__ float red[16 * 128];       // 8 KB: [gate*4+kq2][j*8+b]
    __shared__ float biasS[4][SLU];
    __shared__ float redf[10][16];
    const int blk = blockIdx.x, tid = threadIdx.x;
    const int g = blk >> 5, r = blk & 31;

    if (r < 16)
        run_layer<NF + NH, false, NSLOT, SC1>(g, r, tid, feats, wih0, whh0, bih0, bhh0,
                                              fcw, fcb, h0h, flags, out,
                                              xs, red, biasS, redf);
    else
        run_layer<NH + NH, true, NSLOT, SC1>(g, r - 16, tid, h0h, wih1, whh1, bih1, bhh1,
                                             fcw, fcb, h1h, flags, out,
                                             xs, red, biasS, redf);
}

extern "C" void kernel_launch(void* const* d_in, const int* in_sizes, int n_in,
                              void* d_out, int out_size, void* d_ws, size_t ws_size,
                              hipStream_t stream) {
    (void)in_sizes; (void)n_in; (void)out_size;
    const float* x      = (const float*)d_in[0];
    const float* conv_w = (const float*)d_in[1];
    const float* conv_b = (const float*)d_in[2];
    const float* gamma  = (const float*)d_in[3];
    const float* beta   = (const float*)d_in[4];
    const float* wih0   = (const float*)d_in[5];
    const float* whh0   = (const float*)d_in[6];
    const float* bih0   = (const float*)d_in[7];
    const float* bhh0   = (const float*)d_in[8];
    const float* wih1   = (const float*)d_in[9];
    const float* whh1   = (const float*)d_in[10];
    const float* bih1   = (const float*)d_in[11];
    const float* bhh1   = (const float*)d_in[12];
    const float* fcw    = (const float*)d_in[13];
    const float* fcb    = (const float*)d_in[14];
    float* out = (float*)d_out;

    char* ws = (char*)d_ws;
    const size_t FEATS_B = (size_t)TLEN * NG * NF * GS * 4;        // 33,554,432
    const size_t H_FULL  = (size_t)(TLEN + 1) * NG * GSLAB * 4;    // 134,283,264
    const size_t need_full = 2 * H_FULL + 4096 + FEATS_B + 4096;

    bool full = (ws_size >= need_full);
    float *h0h, *h1h, *feats, *partials;
    int* flags;

    if (full) {
        h0h      = (float*)(ws);
        h1h      = (float*)(ws + H_FULL);
        flags    = (int*)  (ws + 2 * H_FULL);
        feats    = (float*)(ws + 2 * H_FULL + 4096);
        partials = (float*)(ws + 2 * H_FULL + 4096 + FEATS_B);
    } else {
        // fallback: 8-slot rings + LLC-coherent staging loads
        const size_t H_RING = (size_t)8 * NG * GSLAB * 4;          // 524,288
        h0h      = (float*)(ws);
        h1h      = (float*)(ws + H_RING);
        flags    = (int*)  (ws + 2 * H_RING);
        feats    = (float*)(ws + 2 * H_RING + 4096);
        partials = (float*)(ws + 2 * H_RING + 4096 + FEATS_B);
    }

    // Stream-ordered init (replaces cooperative grid.sync): zero flags + h[-1] slots.
    (void)hipMemsetAsync(flags, 0, 4096, stream);
    (void)hipMemsetAsync(h0h, 0, (size_t)NG * GSLAB * 4, stream);  // h0 slot 0
    (void)hipMemsetAsync(h1h, 0, (size_t)NG * GSLAB * 4, stream);  // h1 slot 0

    conv_stats_kernel<<<dim3(256), dim3(256), 0, stream>>>(x, conv_w, conv_b, partials);
    conv_bn_feats_kernel<<<dim3(2048), dim3(256), 0, stream>>>(
        x, conv_w, conv_b, gamma, beta, partials, feats);

    if (full)
        lstm_kernel<TLEN + 1, false><<<dim3(256), dim3(256), 0, stream>>>(
            feats, wih0, whh0, bih0, bhh0, wih1, whh1, bih1, bhh1,
            fcw, fcb, h0h, h1h, flags, out);
    else
        lstm_kernel<8, true><<<dim3(256), dim3(256), 0, stream>>>(
            feats, wih0, whh0, bih0, bhh0, wih1, whh1, bih1, bhh1,
            fcw, fcb, h0h, h1h, flags, out);
}

// Round 9
// 19312.221 us; speedup vs baseline: 2.5416x; 1.2503x over previous
//
#include <hip/hip_runtime.h>

#define TLEN 2048
#define NB   64
#define NH   256
#define NF   64
#define NCIN 16
#define NOUT 20
#define NG   8              // batch groups (sync domains)
#define GS   8              // samples per group
#define SLU  16             // hidden units per slice (block)
#define GSLAB (NH * GS)     // 2048 floats: one group's h slab [unit][sample]
#define NSLOT 8             // h ring depth

// LLC-coherent (sc1) access helpers.
#define HL(p)    __hip_atomic_load((p),      __ATOMIC_RELAXED, __HIP_MEMORY_SCOPE_AGENT)
#define HS(p, v) __hip_atomic_store((p), (v), __ATOMIC_RELAXED, __HIP_MEMORY_SCOPE_AGENT)
// RELEASE publish: guarantees data stores committed before flag visible (ring mode
// correctness hinges on this — r3 passed with it, r8 failed without it).
#define HSREL(p, v) __hip_atomic_store((p), (v), __ATOMIC_RELEASE, __HIP_MEMORY_SCOPE_AGENT)

__device__ __forceinline__ float sigf(float x) { return 1.0f / (1.0f + __expf(-x)); }
__device__ __forceinline__ float tanh_f(float x) {
    x = fminf(fmaxf(x, -15.0f), 15.0f);
    float e = __expf(2.0f * x);
    return (e - 1.0f) / (e + 1.0f);
}

// NOTE: parameter must NOT be named `w` — `xv.w` would get macro-substituted.
#define FMA4(acc, xv, ww) do { \
    acc.x = fmaf(xv.x, (ww), acc.x); \
    acc.y = fmaf(xv.y, (ww), acc.y); \
    acc.z = fmaf(xv.z, (ww), acc.z); \
    acc.w = fmaf(xv.w, (ww), acc.w); } while (0)

#define RED32(vv) do { \
    vv.x += __shfl_xor(vv.x, 32); vv.y += __shfl_xor(vv.y, 32); \
    vv.z += __shfl_xor(vv.z, 32); vv.w += __shfl_xor(vv.w, 32); } while (0)

// ---------------- Pass A: conv + relu, per-(f, t-quarter) partial sums for BN stats
__global__ __launch_bounds__(256) void conv_stats_kernel(
    const float* __restrict__ x, const float* __restrict__ cw, const float* __restrict__ cb,
    float* __restrict__ partials)
{
    const int blk = blockIdx.x;          // 256 blocks
    const int f = blk >> 2, tq = blk & 3;
    const int tid = threadIdx.x;

    float w[NCIN][3];
#pragma unroll
    for (int c = 0; c < NCIN; ++c) {
        w[c][0] = cw[(f * NCIN + c) * 3 + 0];
        w[c][1] = cw[(f * NCIN + c) * 3 + 1];
        w[c][2] = cw[(f * NCIN + c) * 3 + 2];
    }
    const float bias = cb[f];
    float s = 0.f, s2 = 0.f;

    for (int i = 0; i < 128; ++i) {
        int idx = tq * 32768 + i * 256 + tid;   // (B*T)/4 elements per block
        int b = idx >> 11;
        int t = idx & 2047;
        const float* xb = x + (size_t)b * NCIN * TLEN;
        float acc = bias;
#pragma unroll
        for (int c = 0; c < NCIN; ++c) {
            const float* xc = xb + (size_t)c * TLEN + t;
            float xm = (t > 0)        ? xc[-1] : 0.f;
            float x0 = xc[0];
            float xp = (t < TLEN - 1) ? xc[1]  : 0.f;
            acc = fmaf(xm, w[c][0], acc);
            acc = fmaf(x0, w[c][1], acc);
            acc = fmaf(xp, w[c][2], acc);
        }
        float y = fmaxf(acc, 0.f);
        s += y; s2 = fmaf(y, y, s2);
    }

    __shared__ float rs[256], rs2[256];
    rs[tid] = s; rs2[tid] = s2;
    __syncthreads();
    for (int off = 128; off > 0; off >>= 1) {
        if (tid < off) { rs[tid] += rs[tid + off]; rs2[tid] += rs2[tid + off]; }
        __syncthreads();
    }
    if (tid == 0) {
        partials[(f * 4 + tq) * 2 + 0] = rs[0];
        partials[(f * 4 + tq) * 2 + 1] = rs2[0];
    }
}

// ---------------- Pass B: conv + relu + BN affine, write feats[t][g][f][bl]
__global__ __launch_bounds__(256) void conv_bn_feats_kernel(
    const float* __restrict__ x, const float* __restrict__ cw, const float* __restrict__ cb,
    const float* __restrict__ gamma, const float* __restrict__ beta,
    const float* __restrict__ partials, float* __restrict__ feats)
{
    const int t = blockIdx.x;            // 2048 blocks
    const int tid = threadIdx.x;
    const int b = tid & 63, fq = tid >> 6;

    __shared__ float sc[NF], sh[NF];
    if (tid < NF) {
        int f = tid;
        float s = 0.f, s2 = 0.f;
        for (int q = 0; q < 4; ++q) {
            s  += partials[(f * 4 + q) * 2 + 0];
            s2 += partials[(f * 4 + q) * 2 + 1];
        }
        const float inv_n = 1.0f / ((float)NB * (float)TLEN);
        float mean = s * inv_n;
        float var  = s2 * inv_n - mean * mean;
        float iv   = rsqrtf(var + 1e-5f);
        float scale = gamma[f] * iv;
        sc[f] = scale;
        sh[f] = beta[f] - mean * scale;
    }
    __syncthreads();

    float xr[NCIN][3];
    const float* xb = x + (size_t)b * NCIN * TLEN;
#pragma unroll
    for (int c = 0; c < NCIN; ++c) {
        const float* xc = xb + (size_t)c * TLEN + t;
        xr[c][0] = (t > 0)        ? xc[-1] : 0.f;
        xr[c][1] = xc[0];
        xr[c][2] = (t < TLEN - 1) ? xc[1]  : 0.f;
    }

    float* ft = feats + (size_t)t * (NG * NF * GS);
    for (int fi = 0; fi < 16; ++fi) {
        int f = fq * 16 + fi;
        float acc = cb[f];
#pragma unroll
        for (int c = 0; c < NCIN; ++c) {
            acc = fmaf(xr[c][0], cw[(f * NCIN + c) * 3 + 0], acc);
            acc = fmaf(xr[c][1], cw[(f * NCIN + c) * 3 + 1], acc);
            acc = fmaf(xr[c][2], cw[(f * NCIN + c) * 3 + 2], acc);
        }
        float y = fmaxf(acc, 0.f);
        ft[((b >> 3) * NF + f) * GS + (b & 7)] = fmaf(y, sc[f], sh[f]);
    }
}

// ---------------- per-layer driver
// Block = one (group g, slice sl) of one layer. 256 threads:
//   jp = tid&7 (unit pair jp, jp+8), g4 = (tid>>3)&3 (gate), kq = tid>>5 (K-eighth)
// Weights in VGPRs (launch_bounds(256,1) -> no spill). x slab staged to LDS per step;
// staging loads ISSUED before/between flag spins so LLC latency overlaps detection.
// h slot for step t = (t+1)&7; h[-1] in slot 0 (memset pre-dispatch).
template<int K, bool ISL1>
__device__ __forceinline__ void run_layer(
    int g, int sl, int tid,
    const float* __restrict__ xin,   // !ISL1: feats ; ISL1: h0 ring
    const float* __restrict__ wih, const float* __restrict__ whh,
    const float* __restrict__ bih, const float* __restrict__ bhh,
    const float* __restrict__ fcw, const float* __restrict__ fcb,
    float* houth, int* flags, float* __restrict__ out,
    float* xs, float* red, float (*biasS)[SLU], float (*redf)[16])
{
    constexpr int K8 = K / 8;
    const int jp = tid & 7;
    const int g4 = (tid >> 3) & 3;
    const int kq = tid >> 5;
    const int kqBase = kq * K8;
    const int rowA = g4 * 256 + sl * SLU + jp;
    const int rowB = rowA + 8;

    // ---- weights -> registers (once)
    float wa[K8], wb[K8];
#pragma unroll
    for (int kk = 0; kk < K8; ++kk) {
        int k = kqBase + kk;
        if constexpr (!ISL1) {
            wa[kk] = (k < NF) ? wih[rowA * NF + k] : whh[rowA * NH + (k - NF)];
            wb[kk] = (k < NF) ? wih[rowB * NF + k] : whh[rowB * NH + (k - NF)];
        } else {
            wa[kk] = (k < NH) ? wih[rowA * NH + k] : whh[rowA * NH + (k - NH)];
            wb[kk] = (k < NH) ? wih[rowB * NH + k] : whh[rowB * NH + (k - NH)];
        }
    }
    if (tid < 64) {
        int gg = tid >> 4, jj = tid & 15, grow = gg * 256 + sl * SLU + jj;
        biasS[gg][jj] = bih[grow] + bhh[grow];
    }
    __syncthreads();

    const int fj = tid >> 3, fb = tid & 7;  // finalizer mapping (tid<128)
    float c_reg = 0.f;
    int fc = 0;                              // cached flag value (monotone)

    for (int s = 0; s < TLEN; ++s) {
        if constexpr (!ISL1) {
            // ---- feats loads issued first (no dependency); plain cached loads
            const float* fsrc = xin + ((size_t)s * NG + g) * (NF * GS);
            float f0 = fsrc[tid], f1 = fsrc[256 + tid];
            // ---- spin: own-layer h0[s-1] ready + ring overwrite guard vs L1 readers
            for (;;) {
                bool ok = true;
                if (tid < 16)      { if (fc < s) fc = HL(&flags[g * 32 + tid]); ok = fc >= s; }
                else if (tid < 32) { int thr = s + 2 - NSLOT;
                                     if (fc < thr) fc = HL(&flags[g * 32 + tid]); ok = fc >= thr; }
                if (__syncthreads_count(ok) == 256) break;
                __builtin_amdgcn_s_sleep(1);
            }
            // ---- h0[s-1] coherent loads (slot s&7), lane-contiguous per instruction
            const float* hp = houth + ((size_t)(s & 7) * NG + g) * GSLAB;
            float h0r[8];
#pragma unroll
            for (int i = 0; i < 8; ++i) h0r[i] = HL(hp + i * 256 + tid);
            xs[tid] = f0; xs[256 + tid] = f1;
#pragma unroll
            for (int i = 0; i < 8; ++i) xs[512 + i * 256 + tid] = h0r[i];
        } else {
            // ---- spin A: h0[s] ready (L0 runs ahead, usually no wait)
            for (;;) {
                bool ok = true;
                if (tid < 16) { if (fc < s + 1) fc = HL(&flags[g * 32 + tid]); ok = fc >= s + 1; }
                if (__syncthreads_count(ok) == 256) break;
                __builtin_amdgcn_s_sleep(1);
            }
            // issue h0[s] loads (slot (s+1)&7); latency overlaps spin B
            const float* h0c = xin + ((size_t)((s + 1) & 7) * NG + g) * GSLAB;
            float xr0[8];
#pragma unroll
            for (int i = 0; i < 8; ++i) xr0[i] = HL(h0c + i * 256 + tid);
            // ---- spin B: h1[s-1] ready (peer L1 blocks)
            for (;;) {
                bool ok = true;
                if (tid >= 16 && tid < 32) { if (fc < s) fc = HL(&flags[g * 32 + tid]); ok = fc >= s; }
                if (__syncthreads_count(ok) == 256) break;
                __builtin_amdgcn_s_sleep(1);
            }
            const float* h1p = houth + ((size_t)(s & 7) * NG + g) * GSLAB;
            float xr1[8];
#pragma unroll
            for (int i = 0; i < 8; ++i) xr1[i] = HL(h1p + i * 256 + tid);
#pragma unroll
            for (int i = 0; i < 8; ++i) xs[i * 256 + tid] = xr0[i];
#pragma unroll
            for (int i = 0; i < 8; ++i) xs[2048 + i * 256 + tid] = xr1[i];
        }
        __syncthreads();

        // ---- gate GEMM: acc over (2 units x 8 samples), K-eighth per thread
        float4 aA0 = {0,0,0,0}, aA1 = {0,0,0,0}, aB0 = {0,0,0,0}, aB1 = {0,0,0,0};
        const float* xsk = xs + kqBase * GS;
#pragma unroll
        for (int kk = 0; kk < K8; ++kk) {
            float4 x0 = *(const float4*)(xsk + kk * GS);
            float4 x1 = *(const float4*)(xsk + kk * GS + 4);
            float wAv = wa[kk], wBv = wb[kk];
            FMA4(aA0, x0, wAv); FMA4(aA1, x1, wAv);
            FMA4(aB0, x0, wBv); FMA4(aB1, x1, wBv);
        }
        RED32(aA0); RED32(aA1); RED32(aB0); RED32(aB1);
        if ((tid & 32) == 0) {
            int gk = g4 * 4 + (tid >> 6);          // [gate][kq2]
            float4* r4 = (float4*)red;
            r4[gk * 32 + jp * 2 + 0]       = aA0;
            r4[gk * 32 + jp * 2 + 1]       = aA1;
            r4[gk * 32 + (jp + 8) * 2 + 0] = aB0;
            r4[gk * 32 + (jp + 8) * 2 + 1] = aB1;
        }
        __syncthreads();

        // ---- finalize: sum 4 kq2-partials per gate, activations, cell update
        if (tid < 128) {
            float gate[4];
#pragma unroll
            for (int gg = 0; gg < 4; ++gg) {
                float s0 = 0.f;
#pragma unroll
                for (int k2 = 0; k2 < 4; ++k2)
                    s0 += red[(gg * 4 + k2) * 128 + fj * 8 + fb];
                gate[gg] = s0 + biasS[gg][fj];
            }
            float i_ = sigf(gate[0]), f_ = sigf(gate[1]);
            float g_ = tanh_f(gate[2]), o_ = sigf(gate[3]);
            c_reg = fmaf(f_, c_reg, i_ * g_);
            float h = o_ * tanh_f(c_reg);
            float* hout = houth + ((size_t)((s + 1) & 7) * NG + g) * GSLAB;
            HS(&hout[sl * 128 + tid], h);          // (sl*SLU+fj)*GS+fb == sl*128+tid
        }
        __syncthreads();
        // RELEASE publish: wbl2+waitcnt orders the h stores before the flag at LLC.
        if (tid == 0) HSREL(&flags[g * 32 + (ISL1 ? 16 : 0) + sl], s + 1);

        // ---- FC for t = s-1 from staged h1prev (xs rows 256..511); seg-rotated reads
        if constexpr (ISL1) {
            if (s >= 1) {
                if (tid < 160) {
                    int m = tid >> 4, seg = tid & 15;
                    int fo = sl * 10 + m, o = fo >> 3, b = fo & 7;
                    const float* fwr = fcw + o * NH;
                    const float* xr = xs + NH * GS + b;
                    float p = 0.f;
#pragma unroll
                    for (int i2 = 0; i2 < 16; ++i2) {
                        int e = seg * 16 + ((seg + i2) & 15);   // rotation: 16-way -> 4-way bank
                        p = fmaf(fwr[e], xr[e * GS], p);
                    }
                    redf[m][seg] = p;
                }
                __syncthreads();
                if (tid < 10) {
                    int fo = sl * 10 + tid, o = fo >> 3, b = fo & 7;
                    float s0 = 0.f;
#pragma unroll
                    for (int seg = 0; seg < 16; ++seg) s0 += redf[tid][seg];
                    out[((size_t)(g * GS + b) * NOUT + o) * TLEN + (s - 1)] = s0 + fcb[o];
                }
            }
        }
    }

    // ---- epilogue FC for t = TLEN-1
    if constexpr (ISL1) {
        for (;;) {
            bool ok = true;
            if (tid >= 16 && tid < 32) { if (fc < TLEN) fc = HL(&flags[g * 32 + tid]); ok = fc >= TLEN; }
            if (__syncthreads_count(ok) == 256) break;
            __builtin_amdgcn_s_sleep(1);
        }
        const float* hlast = houth + ((size_t)(TLEN & 7) * NG + g) * GSLAB;  // slot 0
#pragma unroll
        for (int i = 0; i < 8; ++i) xs[NH * GS + i * 256 + tid] = HL(hlast + i * 256 + tid);
        __syncthreads();
        if (tid < 160) {
            int m = tid >> 4, seg = tid & 15;
            int fo = sl * 10 + m, o = fo >> 3, b = fo & 7;
            const float* fwr = fcw + o * NH;
            const float* xr = xs + NH * GS + b;
            float p = 0.f;
#pragma unroll
            for (int i2 = 0; i2 < 16; ++i2) {
                int e = seg * 16 + ((seg + i2) & 15);
                p = fmaf(fwr[e], xr[e * GS], p);
            }
            redf[m][seg] = p;
        }
        __syncthreads();
        if (tid < 10) {
            int fo = sl * 10 + tid, o = fo >> 3, b = fo & 7;
            float s0 = 0.f;
#pragma unroll
            for (int seg = 0; seg < 16; ++seg) s0 += redf[tid][seg];
            out[((size_t)(g * GS + b) * NOUT + o) * TLEN + (TLEN - 1)] = s0 + fcb[o];
        }
    }
}

// Grid: 256 blocks x 256 threads, plain launch. Block (g, r): r<16 -> L0 slice r;
// r>=16 -> L1 slice r-16. launch_bounds(256,1): weights must fit in VGPRs (no spill).
__global__ __launch_bounds__(256, 1) void lstm_kernel(
    const float* __restrict__ feats,
    const float* __restrict__ wih0, const float* __restrict__ whh0,
    const float* __restrict__ bih0, const float* __restrict__ bhh0,
    const float* __restrict__ wih1, const float* __restrict__ whh1,
    const float* __restrict__ bih1, const float* __restrict__ bhh1,
    const float* __restrict__ fcw,  const float* __restrict__ fcb,
    float* h0h, float* h1h, int* flags, float* __restrict__ out)
{
    __shared__ float xs[512 * GS];        // 16 KB: x slab [k][b]
    __shared__ float red[16 * 128];       // 8 KB: [gate*4+kq2][j*8+b]
    __shared__ float biasS[4][SLU];
    __shared__ float redf[10][16];
    const int blk = blockIdx.x, tid = threadIdx.x;
    const int g = blk >> 5, r = blk & 31;

    if (r < 16)
        run_layer<NF + NH, false>(g, r, tid, feats, wih0, whh0, bih0, bhh0,
                                  fcw, fcb, h0h, flags, out, xs, red, biasS, redf);
    else
        run_layer<NH + NH, true>(g, r - 16, tid, h0h, wih1, whh1, bih1, bhh1,
                                 fcw, fcb, h1h, flags, out, xs, red, biasS, redf);
}

extern "C" void kernel_launch(void* const* d_in, const int* in_sizes, int n_in,
                              void* d_out, int out_size, void* d_ws, size_t ws_size,
                              hipStream_t stream) {
    (void)in_sizes; (void)n_in; (void)out_size; (void)ws_size;
    const float* x      = (const float*)d_in[0];
    const float* conv_w = (const float*)d_in[1];
    const float* conv_b = (const float*)d_in[2];
    const float* gamma  = (const float*)d_in[3];
    const float* beta   = (const float*)d_in[4];
    const float* wih0   = (const float*)d_in[5];
    const float* whh0   = (const float*)d_in[6];
    const float* bih0   = (const float*)d_in[7];
    const float* bhh0   = (const float*)d_in[8];
    const float* wih1   = (const float*)d_in[9];
    const float* whh1   = (const float*)d_in[10];
    const float* bih1   = (const float*)d_in[11];
    const float* bhh1   = (const float*)d_in[12];
    const float* fcw    = (const float*)d_in[13];
    const float* fcb    = (const float*)d_in[14];
    float* out = (float*)d_out;

    char* ws = (char*)d_ws;
    const size_t H_RING  = (size_t)NSLOT * NG * GSLAB * 4;       // 524,288 B each
    const size_t FEATS_B = (size_t)TLEN * NG * NF * GS * 4;      // 33,554,432 B

    float* h0h      = (float*)(ws);
    float* h1h      = (float*)(ws + H_RING);
    int*   flags    = (int*)  (ws + 2 * H_RING);
    float* feats    = (float*)(ws + 2 * H_RING + 4096);
    float* partials = (float*)(ws + 2 * H_RING + 4096 + FEATS_B);

    // Stream-ordered init: zero flags + h[-1] slots (slot 0 of each ring).
    (void)hipMemsetAsync(flags, 0, 4096, stream);
    (void)hipMemsetAsync(h0h, 0, (size_t)NG * GSLAB * 4, stream);
    (void)hipMemsetAsync(h1h, 0, (size_t)NG * GSLAB * 4, stream);

    conv_stats_kernel<<<dim3(256), dim3(256), 0, stream>>>(x, conv_w, conv_b, partials);
    conv_bn_feats_kernel<<<dim3(2048), dim3(256), 0, stream>>>(
        x, conv_w, conv_b, gamma, beta, partials, feats);

    lstm_kernel<<<dim3(256), dim3(256), 0, stream>>>(
        feats, wih0, whh0, bih0, bhh0, wih1, whh1, bih1, bhh1,
        fcw, fcb, h0h, h1h, flags, out);
}

// Round 10
// 17285.004 us; speedup vs baseline: 2.8397x; 1.1173x over previous
//
#include <hip/hip_runtime.h>

#define TLEN 2048
#define NB   64
#define NH   256
#define NF   64
#define NCIN 16
#define NOUT 20
#define NG   8              // batch groups (sync domains)
#define GS   8              // samples per group
#define SLU  16             // hidden units per slice (block)
#define GSLAB (NH * GS)     // 2048 floats: one group's h slab [unit][sample]
#define NSLOT 8             // h ring depth

// LLC-coherent (sc1) access helpers.
#define HL(p)    __hip_atomic_load((p),      __ATOMIC_RELAXED, __HIP_MEMORY_SCOPE_AGENT)
#define HS(p, v) __hip_atomic_store((p), (v), __ATOMIC_RELAXED, __HIP_MEMORY_SCOPE_AGENT)

__device__ __forceinline__ float poison_f() { return __uint_as_float(0xFFFFFFFFu); }

__device__ __forceinline__ float sigf(float x) { return 1.0f / (1.0f + __expf(-x)); }
__device__ __forceinline__ float tanh_f(float x) {
    x = fminf(fmaxf(x, -15.0f), 15.0f);
    float e = __expf(2.0f * x);
    return (e - 1.0f) / (e + 1.0f);
}

// NOTE: parameter must NOT be named `w` — `xv.w` would get macro-substituted.
#define FMA4(acc, xv, ww) do { \
    acc.x = fmaf(xv.x, (ww), acc.x); \
    acc.y = fmaf(xv.y, (ww), acc.y); \
    acc.z = fmaf(xv.z, (ww), acc.z); \
    acc.w = fmaf(xv.w, (ww), acc.w); } while (0)

#define RED32(vv) do { \
    vv.x += __shfl_xor(vv.x, 32); vv.y += __shfl_xor(vv.y, 32); \
    vv.z += __shfl_xor(vv.z, 32); vv.w += __shfl_xor(vv.w, 32); } while (0)

// ---------------- Pass A: conv + relu, per-(f, t-quarter) partial sums for BN stats
__global__ __launch_bounds__(256) void conv_stats_kernel(
    const float* __restrict__ x, const float* __restrict__ cw, const float* __restrict__ cb,
    float* __restrict__ partials)
{
    const int blk = blockIdx.x;          // 256 blocks
    const int f = blk >> 2, tq = blk & 3;
    const int tid = threadIdx.x;

    float w[NCIN][3];
#pragma unroll
    for (int c = 0; c < NCIN; ++c) {
        w[c][0] = cw[(f * NCIN + c) * 3 + 0];
        w[c][1] = cw[(f * NCIN + c) * 3 + 1];
        w[c][2] = cw[(f * NCIN + c) * 3 + 2];
    }
    const float bias = cb[f];
    float s = 0.f, s2 = 0.f;

    for (int i = 0; i < 128; ++i) {
        int idx = tq * 32768 + i * 256 + tid;   // (B*T)/4 elements per block
        int b = idx >> 11;
        int t = idx & 2047;
        const float* xb = x + (size_t)b * NCIN * TLEN;
        float acc = bias;
#pragma unroll
        for (int c = 0; c < NCIN; ++c) {
            const float* xc = xb + (size_t)c * TLEN + t;
            float xm = (t > 0)        ? xc[-1] : 0.f;
            float x0 = xc[0];
            float xp = (t < TLEN - 1) ? xc[1]  : 0.f;
            acc = fmaf(xm, w[c][0], acc);
            acc = fmaf(x0, w[c][1], acc);
            acc = fmaf(xp, w[c][2], acc);
        }
        float y = fmaxf(acc, 0.f);
        s += y; s2 = fmaf(y, y, s2);
    }

    __shared__ float rs[256], rs2[256];
    rs[tid] = s; rs2[tid] = s2;
    __syncthreads();
    for (int off = 128; off > 0; off >>= 1) {
        if (tid < off) { rs[tid] += rs[tid + off]; rs2[tid] += rs2[tid + off]; }
        __syncthreads();
    }
    if (tid == 0) {
        partials[(f * 4 + tq) * 2 + 0] = rs[0];
        partials[(f * 4 + tq) * 2 + 1] = rs2[0];
    }
}

// ---------------- Pass B: conv + relu + BN affine, write feats[t][g][f][bl]
__global__ __launch_bounds__(256) void conv_bn_feats_kernel(
    const float* __restrict__ x, const float* __restrict__ cw, const float* __restrict__ cb,
    const float* __restrict__ gamma, const float* __restrict__ beta,
    const float* __restrict__ partials, float* __restrict__ feats)
{
    const int t = blockIdx.x;            // 2048 blocks
    const int tid = threadIdx.x;
    const int b = tid & 63, fq = tid >> 6;

    __shared__ float sc[NF], sh[NF];
    if (tid < NF) {
        int f = tid;
        float s = 0.f, s2 = 0.f;
        for (int q = 0; q < 4; ++q) {
            s  += partials[(f * 4 + q) * 2 + 0];
            s2 += partials[(f * 4 + q) * 2 + 1];
        }
        const float inv_n = 1.0f / ((float)NB * (float)TLEN);
        float mean = s * inv_n;
        float var  = s2 * inv_n - mean * mean;
        float iv   = rsqrtf(var + 1e-5f);
        float scale = gamma[f] * iv;
        sc[f] = scale;
        sh[f] = beta[f] - mean * scale;
    }
    __syncthreads();

    float xr[NCIN][3];
    const float* xb = x + (size_t)b * NCIN * TLEN;
#pragma unroll
    for (int c = 0; c < NCIN; ++c) {
        const float* xc = xb + (size_t)c * TLEN + t;
        xr[c][0] = (t > 0)        ? xc[-1] : 0.f;
        xr[c][1] = xc[0];
        xr[c][2] = (t < TLEN - 1) ? xc[1]  : 0.f;
    }

    float* ft = feats + (size_t)t * (NG * NF * GS);
    for (int fi = 0; fi < 16; ++fi) {
        int f = fq * 16 + fi;
        float acc = cb[f];
#pragma unroll
        for (int c = 0; c < NCIN; ++c) {
            acc = fmaf(xr[c][0], cw[(f * NCIN + c) * 3 + 0], acc);
            acc = fmaf(xr[c][1], cw[(f * NCIN + c) * 3 + 1], acc);
            acc = fmaf(xr[c][2], cw[(f * NCIN + c) * 3 + 2], acc);
        }
        float y = fmaxf(acc, 0.f);
        ft[((b >> 3) * NF + f) * GS + (b & 7)] = fmaf(y, sc[f], sh[f]);
    }
}

// =====================================================================
// NaN-poison protocol (no flags, no release fences):
//   - rings pre-poisoned 0xFF (= NaN); h[-1] slot 0 = 0.0
//   - h[m] lives in slot (m+1)&7; producer writes value, consumer retries while NaN
//   - producer at step s re-poisons slot (s+5)&7 (holds h[s-4])
//   - L0 guard before poisoning h0[s-4]: sentinel h1[s-3] present for all 16 L1
//     slices => every L1 block finished step s-3 => done reading h0[s-4].
//     (lag induction: L0-L1 gap <= 5 < 8, so stale-generation false-pass impossible)
//   - intra-layer readers are lockstep +-1 by construction (each block reads all
//     peers' slices every step)
// =====================================================================

// ---------------- layer-0 block (slice sl of group g)
__device__ __forceinline__ void run_l0(
    int g, int sl, int tid,
    const float* __restrict__ feats,
    const float* __restrict__ wih, const float* __restrict__ whh,
    const float* __restrict__ bih, const float* __restrict__ bhh,
    float* h0, const float* h1,
    float* xs, float* red, float (*biasS)[SLU])
{
    constexpr int K8 = (NF + NH) / 8;     // 40
    const int jp = tid & 7;
    const int g4 = (tid >> 3) & 3;
    const int kq = tid >> 5;
    const int rowA = g4 * 256 + sl * SLU + jp;
    const int rowB = rowA + 8;

    float wa[K8], wb[K8];
#pragma unroll
    for (int kk = 0; kk < K8; ++kk) {
        int k = kq * K8 + kk;
        wa[kk] = (k < NF) ? wih[rowA * NF + k] : whh[rowA * NH + (k - NF)];
        wb[kk] = (k < NF) ? wih[rowB * NF + k] : whh[rowB * NH + (k - NF)];
    }
    if (tid < 64) {
        int gg = tid >> 4, jj = tid & 15, grow = gg * 256 + sl * SLU + jj;
        biasS[gg][jj] = bih[grow] + bhh[grow];
    }
    __syncthreads();

    const int fj = tid >> 3, fb = tid & 7;
    float c_reg = 0.f;
    const int sj = (tid >= 128 && tid < 144) ? tid - 128 : 0;   // sentinel slice id

    for (int s = 0; s < TLEN; ++s) {
        // feats: plain cached loads, no sync needed
        const float* fsrc = feats + ((size_t)s * NG + g) * (NF * GS);
        float f0 = fsrc[tid], f1 = fsrc[256 + tid];
        // h0[s-1] in slot s&7; sentinel h1[s-3] in slot (s-2)&7
        const float* hp   = h0 + ((size_t)(s & 7) * NG + g) * GSLAB + tid;
        const float* sent = h1 + ((size_t)((s + 6) & 7) * NG + g) * GSLAB + sj * 128;
        float hv[8];
        for (;;) {
            bool bad = false;
#pragma unroll
            for (int i = 0; i < 8; ++i) { hv[i] = HL(hp + i * 256); if (hv[i] != hv[i]) bad = true; }
            if (s >= 3 && tid >= 128 && tid < 144) {
                float sv = HL(sent); if (sv != sv) bad = true;
            }
            if (__syncthreads_count(bad) == 0) break;
            __builtin_amdgcn_s_sleep(2);
        }
        xs[tid] = f0; xs[256 + tid] = f1;
#pragma unroll
        for (int i = 0; i < 8; ++i) xs[512 + i * 256 + tid] = hv[i];
        __syncthreads();

        // gate GEMM, K8=40
        float4 aA0 = {0,0,0,0}, aA1 = {0,0,0,0}, aB0 = {0,0,0,0}, aB1 = {0,0,0,0};
        const float* xsk = xs + kq * (K8 * GS);
#pragma unroll
        for (int kk = 0; kk < K8; ++kk) {
            float4 x0 = *(const float4*)(xsk + kk * GS);
            float4 x1 = *(const float4*)(xsk + kk * GS + 4);
            float wAv = wa[kk], wBv = wb[kk];
            FMA4(aA0, x0, wAv); FMA4(aA1, x1, wAv);
            FMA4(aB0, x0, wBv); FMA4(aB1, x1, wBv);
        }
        RED32(aA0); RED32(aA1); RED32(aB0); RED32(aB1);
        if ((tid & 32) == 0) {
            int gk = g4 * 4 + (tid >> 6);
            float4* r4 = (float4*)red;
            r4[gk * 32 + jp * 2 + 0]       = aA0;
            r4[gk * 32 + jp * 2 + 1]       = aA1;
            r4[gk * 32 + (jp + 8) * 2 + 0] = aB0;
            r4[gk * 32 + (jp + 8) * 2 + 1] = aB1;
        }
        __syncthreads();

        if (tid < 128) {
            float gate[4];
#pragma unroll
            for (int gg = 0; gg < 4; ++gg) {
                float s0 = 0.f;
#pragma unroll
                for (int k2 = 0; k2 < 4; ++k2)
                    s0 += red[(gg * 4 + k2) * 128 + fj * 8 + fb];
                gate[gg] = s0 + biasS[gg][fj];
            }
            float i_ = sigf(gate[0]), f_ = sigf(gate[1]);
            float g_ = tanh_f(gate[2]), o_ = sigf(gate[3]);
            c_reg = fmaf(f_, c_reg, i_ * g_);
            float h = o_ * tanh_f(c_reg);
            HS(&h0[((size_t)((s + 1) & 7) * NG + g) * GSLAB + sl * 128 + tid], h);
            // re-poison slot (s+5)&7 (= h0[s-4]); guarded by the sentinel above
            HS(&h0[((size_t)((s + 5) & 7) * NG + g) * GSLAB + sl * 128 + tid], poison_f());
        }
        // no trailing barrier: next retry loop's __syncthreads_count synchronizes
    }
}

// ---------------- layer-1 block (slice sl of group g), FC fused
__device__ __forceinline__ void run_l1(
    int g, int sl, int tid,
    const float* __restrict__ h0,
    const float* __restrict__ wih, const float* __restrict__ whh,
    const float* __restrict__ bih, const float* __restrict__ bhh,
    const float* __restrict__ fcw, const float* __restrict__ fcb,
    float* h1, float* __restrict__ out,
    float* xs, float* red, float (*biasS)[SLU])
{
    constexpr int K8 = (NH + NH) / 8;     // 64
    const int jp = tid & 7;
    const int g4 = (tid >> 3) & 3;
    const int kq = tid >> 5;
    const int rowA = g4 * 256 + sl * SLU + jp;
    const int rowB = rowA + 8;

    float wa[K8], wb[K8];
#pragma unroll
    for (int kk = 0; kk < K8; ++kk) {
        int k = kq * K8 + kk;
        wa[kk] = (k < NH) ? wih[rowA * NH + k] : whh[rowA * NH + (k - NH)];
        wb[kk] = (k < NH) ? wih[rowB * NH + k] : whh[rowB * NH + (k - NH)];
    }
    if (tid < 64) {
        int gg = tid >> 4, jj = tid & 15, grow = gg * 256 + sl * SLU + jj;
        biasS[gg][jj] = bih[grow] + bhh[grow];
    }
    __syncthreads();

    const int fj = tid >> 3, fb = tid & 7;
    float c_reg = 0.f;
    // FC lane mapping (tid < 160): m = tid>>4 (output slot), seg = tid&15
    const int fm = tid >> 4, fseg = tid & 15;
    const int ffo = sl * 10 + fm;                 // in [0,160)
    const int fo_o = ffo >> 3, fo_b = ffo & 7;

    for (int s = 0; s < TLEN; ++s) {
        // h0[s] in slot (s+1)&7 ; h1[s-1] in slot s&7
        const float* h0c = h0 + ((size_t)((s + 1) & 7) * NG + g) * GSLAB + tid;
        const float* h1p = h1 + ((size_t)(s & 7) * NG + g) * GSLAB + tid;
        float xr0[8], xr1[8];
        for (;;) {
            bool bad = false;
#pragma unroll
            for (int i = 0; i < 8; ++i) { xr0[i] = HL(h0c + i * 256); if (xr0[i] != xr0[i]) bad = true; }
#pragma unroll
            for (int i = 0; i < 8; ++i) { xr1[i] = HL(h1p + i * 256); if (xr1[i] != xr1[i]) bad = true; }
            if (__syncthreads_count(bad) == 0) break;
            __builtin_amdgcn_s_sleep(2);
        }
#pragma unroll
        for (int i = 0; i < 8; ++i) xs[i * 256 + tid] = xr0[i];
#pragma unroll
        for (int i = 0; i < 8; ++i) xs[2048 + i * 256 + tid] = xr1[i];
        __syncthreads();

        // gate GEMM, K8=64
        float4 aA0 = {0,0,0,0}, aA1 = {0,0,0,0}, aB0 = {0,0,0,0}, aB1 = {0,0,0,0};
        const float* xsk = xs + kq * (K8 * GS);
#pragma unroll
        for (int kk = 0; kk < K8; ++kk) {
            float4 x0 = *(const float4*)(xsk + kk * GS);
            float4 x1 = *(const float4*)(xsk + kk * GS + 4);
            float wAv = wa[kk], wBv = wb[kk];
            FMA4(aA0, x0, wAv); FMA4(aA1, x1, wAv);
            FMA4(aB0, x0, wBv); FMA4(aB1, x1, wBv);
        }
        RED32(aA0); RED32(aA1); RED32(aB0); RED32(aB1);
        if ((tid & 32) == 0) {
            int gk = g4 * 4 + (tid >> 6);
            float4* r4 = (float4*)red;
            r4[gk * 32 + jp * 2 + 0]       = aA0;
            r4[gk * 32 + jp * 2 + 1]       = aA1;
            r4[gk * 32 + (jp + 8) * 2 + 0] = aB0;
            r4[gk * 32 + (jp + 8) * 2 + 1] = aB1;
        }
        __syncthreads();

        if (tid < 128) {
            float gate[4];
#pragma unroll
            for (int gg = 0; gg < 4; ++gg) {
                float s0 = 0.f;
#pragma unroll
                for (int k2 = 0; k2 < 4; ++k2)
                    s0 += red[(gg * 4 + k2) * 128 + fj * 8 + fb];
                gate[gg] = s0 + biasS[gg][fj];
            }
            float i_ = sigf(gate[0]), f_ = sigf(gate[1]);
            float g_ = tanh_f(gate[2]), o_ = sigf(gate[3]);
            c_reg = fmaf(f_, c_reg, i_ * g_);
            float h = o_ * tanh_f(c_reg);
            HS(&h1[((size_t)((s + 1) & 7) * NG + g) * GSLAB + sl * 128 + tid], h);
            // re-poison slot (s+5)&7 (= h1[s-4]); peers are lockstep +-1, safe
            HS(&h1[((size_t)((s + 5) & 7) * NG + g) * GSLAB + sl * 128 + tid], poison_f());
        }

        // FC for t = s-1 from staged h1prev (xs[2048..]); shuffle-reduce, no barrier
        if (s >= 1 && tid < 160) {
            const float* fwr = fcw + fo_o * NH;
            const float* xr = xs + NH * GS + fo_b;
            float p = 0.f;
#pragma unroll
            for (int i2 = 0; i2 < 16; ++i2) {
                int e = fseg * 16 + ((fseg + i2) & 15);   // bank rotation
                p = fmaf(fwr[e], xr[e * GS], p);
            }
#pragma unroll
            for (int d = 1; d < 16; d <<= 1) p += __shfl_xor(p, d, 16);
            if (fseg == 0)
                out[((size_t)(g * GS + fo_b) * NOUT + fo_o) * TLEN + (s - 1)] = p + fcb[fo_o];
        }
    }

    // epilogue FC for t = TLEN-1: validate-load h1[TLEN-1] (slot 0)
    {
        const float* hlast = h1 + ((size_t)(TLEN & 7) * NG + g) * GSLAB + tid;
        float xr1[8];
        for (;;) {
            bool bad = false;
#pragma unroll
            for (int i = 0; i < 8; ++i) { xr1[i] = HL(hlast + i * 256); if (xr1[i] != xr1[i]) bad = true; }
            if (__syncthreads_count(bad) == 0) break;
            __builtin_amdgcn_s_sleep(2);
        }
#pragma unroll
        for (int i = 0; i < 8; ++i) xs[2048 + i * 256 + tid] = xr1[i];
        __syncthreads();
        if (tid < 160) {
            const float* fwr = fcw + fo_o * NH;
            const float* xr = xs + NH * GS + fo_b;
            float p = 0.f;
#pragma unroll
            for (int i2 = 0; i2 < 16; ++i2) {
                int e = fseg * 16 + ((fseg + i2) & 15);
                p = fmaf(fwr[e], xr[e * GS], p);
            }
#pragma unroll
            for (int d = 1; d < 16; d <<= 1) p += __shfl_xor(p, d, 16);
            if (fseg == 0)
                out[((size_t)(g * GS + fo_b) * NOUT + fo_o) * TLEN + (TLEN - 1)] = p + fcb[fo_o];
        }
    }
}

// Grid: 256 blocks x 256 threads, plain launch. Block (g, r): r<16 -> L0 slice r;
// r>=16 -> L1 slice r-16. launch_bounds(256,1): weights live in VGPRs (no spill).
__global__ __launch_bounds__(256, 1) void lstm_kernel(
    const float* __restrict__ feats,
    const float* __restrict__ wih0, const float* __restrict__ whh0,
    const float* __restrict__ bih0, const float* __restrict__ bhh0,
    const float* __restrict__ wih1, const float* __restrict__ whh1,
    const float* __restrict__ bih1, const float* __restrict__ bhh1,
    const float* __restrict__ fcw,  const float* __restrict__ fcb,
    float* h0h, float* h1h, float* __restrict__ out)
{
    __shared__ float xs[512 * GS];        // 16 KB
    __shared__ float red[16 * 128];       // 8 KB
    __shared__ float biasS[4][SLU];
    const int blk = blockIdx.x, tid = threadIdx.x;
    const int g = blk >> 5, r = blk & 31;

    if (r < 16)
        run_l0(g, r, tid, feats, wih0, whh0, bih0, bhh0,
               h0h, h1h, xs, red, biasS);
    else
        run_l1(g, r - 16, tid, h0h, wih1, whh1, bih1, bhh1,
               fcw, fcb, h1h, out, xs, red, biasS);
}

extern "C" void kernel_launch(void* const* d_in, const int* in_sizes, int n_in,
                              void* d_out, int out_size, void* d_ws, size_t ws_size,
                              hipStream_t stream) {
    (void)in_sizes; (void)n_in; (void)out_size; (void)ws_size;
    const float* x      = (const float*)d_in[0];
    const float* conv_w = (const float*)d_in[1];
    const float* conv_b = (const float*)d_in[2];
    const float* gamma  = (const float*)d_in[3];
    const float* beta   = (const float*)d_in[4];
    const float* wih0   = (const float*)d_in[5];
    const float* whh0   = (const float*)d_in[6];
    const float* bih0   = (const float*)d_in[7];
    const float* bhh0   = (const float*)d_in[8];
    const float* wih1   = (const float*)d_in[9];
    const float* whh1   = (const float*)d_in[10];
    const float* bih1   = (const float*)d_in[11];
    const float* bhh1   = (const float*)d_in[12];
    const float* fcw    = (const float*)d_in[13];
    const float* fcb    = (const float*)d_in[14];
    float* out = (float*)d_out;

    char* ws = (char*)d_ws;
    const size_t H_RING  = (size_t)NSLOT * NG * GSLAB * 4;       // 524,288 B each
    const size_t SLOT0_B = (size_t)NG * GSLAB * 4;               // 65,536 B
    const size_t FEATS_B = (size_t)TLEN * NG * NF * GS * 4;      // 33,554,432 B

    float* h0h      = (float*)(ws);
    float* h1h      = (float*)(ws + H_RING);
    float* feats    = (float*)(ws + 2 * H_RING);
    float* partials = (float*)(ws + 2 * H_RING + FEATS_B);

    // Poison rings with 0xFF (= NaN), then zero slot 0 (h[-1]).
    (void)hipMemsetAsync(h0h, 0xFF, H_RING, stream);
    (void)hipMemsetAsync(h1h, 0xFF, H_RING, stream);
    (void)hipMemsetAsync(h0h, 0x00, SLOT0_B, stream);
    (void)hipMemsetAsync(h1h, 0x00, SLOT0_B, stream);

    conv_stats_kernel<<<dim3(256), dim3(256), 0, stream>>>(x, conv_w, conv_b, partials);
    conv_bn_feats_kernel<<<dim3(2048), dim3(256), 0, stream>>>(
        x, conv_w, conv_b, gamma, beta, partials, feats);

    lstm_kernel<<<dim3(256), dim3(256), 0, stream>>>(
        feats, wih0, whh0, bih0, bhh0, wih1, whh1, bih1, bhh1,
        fcw, fcb, h0h, h1h, out);
}